// Round 13
// baseline (47.630 us; speedup 1.0000x reference)
//
#include <hip/hip_runtime.h>
#include <hip/hip_fp16.h>

// Unsharp-mask: out = img + param * (img - gaussblur25(img)), param = 5*(tanh(f[b,0])*.5+.5)
// img: (16,3,512,512) fp32. Output: [out (12582912 fp32)] ++ [param (16 fp32)].
//
// R13: R12 pipeline (stage f16 -> dot2 H from LDS -> V + epilogue) at 64x32
// tiles: LDS 19.7 KB -> 8 blocks/CU (was 5) -> 32 waves/CU to hide the
// stage-phase HBM latency that R12's counters showed exposed (39% occ,
// VALU 38%, HBM 30%, nothing saturated). All phases statically unrolled
// with uniform slots so consecutive slots' loads jam (more MLP per wave).

#define RADIUS 12
#define KS     25
#define TILE_X 64
#define TILE_Y 32
#define PT_Y   (TILE_Y + 2 * RADIUS)  // 56
#define TA_LD  104                    // tileA f16 stride: 208B/row -> distinct row bank offsets
#define TB_LD  72                     // tmpB  f16 stride: 144B/row
#define IMG_W  512
#define IMG_H  512
#define PLANE  (IMG_W * IMG_H)
#define NPLANE 48

#define N_STAGE (PT_Y * 11)           // 616 8px-slots
#define N_H     (PT_Y * (TILE_X / 8)) // 448 8-output slots

// Normalized 25-tap Gaussian, sigma=5
__device__ __constant__ float GW[KS] = {
    0.00453456f, 0.00718308f, 0.01093238f, 0.01598625f, 0.02245983f,
    0.03031760f, 0.03931982f, 0.04899550f, 0.05865827f, 0.06747307f,
    0.07456928f, 0.07918039f, 0.08077993f, 0.07918039f, 0.07456928f,
    0.06747307f, 0.05865827f, 0.04899550f, 0.03931982f, 0.03031760f,
    0.02245983f, 0.01598625f, 0.01093238f, 0.00718308f, 0.00453456f
};

__device__ __forceinline__ int reflect512(int i) {
    i = (i < 0) ? -i : i;
    return (i >= 512) ? (1022 - i) : i;
}

typedef _Float16 h2_t __attribute__((ext_vector_type(2)));

__device__ __forceinline__ unsigned h2u(__half2 h) {
    union { __half2 h; unsigned u; } x; x.h = h; return x.u;
}
__device__ __forceinline__ float u_lo(unsigned u) {
    union { unsigned u; __half2 h; } x; x.u = u;
    return __half2float(__low2half(x.h));
}
__device__ __forceinline__ float u_hi(unsigned u) {
    union { unsigned u; __half2 h; } x; x.u = u;
    return __half2float(__high2half(x.h));
}

#if __has_builtin(__builtin_amdgcn_fdot2)
__device__ __forceinline__ float fdot2u(unsigned a, unsigned b, float c) {
    union { unsigned u; h2_t h; } ua, ub;
    ua.u = a; ub.u = b;
    return __builtin_amdgcn_fdot2(ua.h, ub.h, c, false);
}
#else
__device__ __forceinline__ float fdot2u(unsigned a, unsigned b, float c) {
    return c + u_lo(a) * u_lo(b) + u_hi(a) * u_hi(b);
}
#endif

__global__ __launch_bounds__(256) void usm_fused_kernel(
    const float* __restrict__ img, const float* __restrict__ feat,
    float* __restrict__ out, float* __restrict__ out_param)
{
    __shared__ __half tileA[PT_Y][TA_LD];   // 56x104 f16 = 11.6 KB (cols 0..87 used)
    __shared__ __half tmpB[PT_Y][TB_LD];    // 56x72  f16 =  8.1 KB (cols 0..63 used)

    const int tid = threadIdx.x;
    const int tx0 = blockIdx.x * TILE_X, ty0 = blockIdx.y * TILE_Y;
    const int zc = blockIdx.z, b = zc / 3;
    const float param = (tanhf(feat[b * 8]) * 0.5f + 0.5f) * 5.0f;
    const float* __restrict__ src = img + (size_t)zc * PLANE;
    const bool xedge = (blockIdx.x == 0) || (blockIdx.x == 7);

    // Weight pairs for dot2
    unsigned W2[12];
#pragma unroll
    for (int m = 0; m < 12; ++m)
        W2[m] = h2u(__floats2half2_rn(GW[2 * m], GW[2 * m + 1]));
    const unsigned WE = h2u(__floats2half2_rn(GW[24], 0.f));
    const unsigned WO = h2u(__floats2half2_rn(0.f, GW[24]));

    // ---- Stage 56x88 padded tile as f16: 616 slots; slots 0,1 unconditional ----
#pragma unroll
    for (int it = 0; it < 3; ++it) {
        const int li = tid + it * 256;
        if (it < 2 || li < N_STAGE) {
            const int py = li / 11, s = li - py * 11;
            const int gy = reflect512(ty0 - RADIUS + py);
            const float* __restrict__ rowp = src + (size_t)gy * IMG_W;
            const int gx = tx0 - RADIUS + s * 8;
            float4 va, vb;
            if (!xedge) {
                va = *(const float4*)(rowp + gx);
                vb = *(const float4*)(rowp + gx + 4);
            } else {
                va.x = rowp[reflect512(gx)];     va.y = rowp[reflect512(gx + 1)];
                va.z = rowp[reflect512(gx + 2)]; va.w = rowp[reflect512(gx + 3)];
                vb.x = rowp[reflect512(gx + 4)]; vb.y = rowp[reflect512(gx + 5)];
                vb.z = rowp[reflect512(gx + 6)]; vb.w = rowp[reflect512(gx + 7)];
            }
            uint4 pk;
            pk.x = h2u(__floats2half2_rn(va.x, va.y));
            pk.y = h2u(__floats2half2_rn(va.z, va.w));
            pk.z = h2u(__floats2half2_rn(vb.x, vb.y));
            pk.w = h2u(__floats2half2_rn(vb.z, vb.w));
            *(uint4*)&tileA[py][s * 8] = pk;
        }
    }
    __syncthreads();

    // ---- Horizontal via dot2: 448 slots; slot 0 unconditional ----
#pragma unroll
    for (int it = 0; it < 2; ++it) {
        const int li = tid + it * 256;
        if (it < 1 || li < N_H) {
            const int py = li >> 3, g = li & 7;
            const uint4 qa = *(const uint4*)&tileA[py][g * 8];
            const uint4 qb = *(const uint4*)&tileA[py][g * 8 + 8];
            const uint4 qc = *(const uint4*)&tileA[py][g * 8 + 16];
            const uint4 qd = *(const uint4*)&tileA[py][g * 8 + 24];

            unsigned P[16] = { qa.x, qa.y, qa.z, qa.w, qb.x, qb.y, qb.z, qb.w,
                               qc.x, qc.y, qc.z, qc.w, qd.x, qd.y, qd.z, qd.w };
            unsigned S[15];
#pragma unroll
            for (int i = 0; i < 15; ++i)
                S[i] = __builtin_amdgcn_alignbit(P[i + 1], P[i], 16);

            float acc[8];
#pragma unroll
            for (int h = 0; h < 4; ++h) {
                float a = 0.f;
#pragma unroll
                for (int m = 0; m < 12; ++m) a = fdot2u(P[h + m], W2[m], a);
                acc[2 * h] = fdot2u(P[h + 12], WE, a);
            }
#pragma unroll
            for (int h = 0; h < 4; ++h) {
                float a = 0.f;
#pragma unroll
                for (int m = 0; m < 12; ++m) a = fdot2u(S[h + m], W2[m], a);
                acc[2 * h + 1] = fdot2u(P[h + 12], WO, a);
            }

            uint4 pk;
            pk.x = h2u(__floats2half2_rn(acc[0], acc[1]));
            pk.y = h2u(__floats2half2_rn(acc[2], acc[3]));
            pk.z = h2u(__floats2half2_rn(acc[4], acc[5]));
            pk.w = h2u(__floats2half2_rn(acc[6], acc[7]));
            *(uint4*)&tmpB[py][g * 8] = pk;
        }
    }
    __syncthreads();

    // ---- Vertical + epilogue: 4 cols x 2 rows per thread (exactly 256 units) ----
    const int tx4 = (tid & 15) * 4;
    const int ry0 = (tid >> 4) * 2;           // 2 output rows: ry0, ry0+1
    float ax[2], ay[2], az[2], aw[2];
#pragma unroll
    for (int d = 0; d < 2; ++d) ax[d] = ay[d] = az[d] = aw[d] = 0.f;

#pragma unroll
    for (int k = 0; k < KS + 1; ++k) {        // 26 b64 row reads
        uint2 rd = *(const uint2*)&tmpB[ry0 + k][tx4];
        const float c0 = u_lo(rd.x), c1 = u_hi(rd.x);
        const float c2 = u_lo(rd.y), c3 = u_hi(rd.y);
#pragma unroll
        for (int d = 0; d < 2; ++d) {
            const int kk = k - d;
            if (kk >= 0 && kk < KS) {
                const float wk = GW[kk];
                ax[d] += wk * c0; ay[d] += wk * c1;
                az[d] += wk * c2; aw[d] += wk * c3;
            }
        }
    }

    float* __restrict__ dst = out + (size_t)zc * PLANE;
#pragma unroll
    for (int d = 0; d < 2; ++d) {
        const int oy = ty0 + ry0 + d;
        float4 v = *(const float4*)(src + (size_t)oy * IMG_W + tx0 + tx4);  // exact f32
        float4 o;
        o.x = v.x + param * (v.x - ax[d]);
        o.y = v.y + param * (v.y - ay[d]);
        o.z = v.z + param * (v.z - az[d]);
        o.w = v.w + param * (v.w - aw[d]);
        *(float4*)(dst + (size_t)oy * IMG_W + tx0 + tx4) = o;
    }

    if (tid == 0 && blockIdx.x == 0 && blockIdx.y == 0 && (zc - b * 3) == 0)
        out_param[b] = param;
}

extern "C" void kernel_launch(void* const* d_in, const int* in_sizes, int n_in,
                              void* d_out, int out_size, void* d_ws, size_t ws_size,
                              hipStream_t stream) {
    const float* img  = (const float*)d_in[0];
    const float* feat = (const float*)d_in[1];
    float* out       = (float*)d_out;
    float* out_param = (float*)d_out + (size_t)NPLANE * PLANE;

    usm_fused_kernel<<<dim3(IMG_W / TILE_X, IMG_H / TILE_Y, NPLANE), 256, 0, stream>>>(
        img, feat, out, out_param);
}

// Round 14
// 42.192 us; speedup vs baseline: 1.1289x; 1.1289x over previous
//
#include <hip/hip_runtime.h>
#include <hip/hip_fp16.h>

// Unsharp-mask: out = img + param * (img - gaussblur25(img)), param = 5*(tanh(f[b,0])*.5+.5)
// img: (16,3,512,512) fp32. Output: [out (12582912 fp32)] ++ [param (16 fp32)].
//
// R14: R12 pipeline (stage f16 -> dot2 H -> f32 V + epilogue) with IN-PLACE
// LDS: H holds its outputs in registers across a barrier and writes them back
// into tileA cols 0..63 (tmpB deleted). LDS 31.2 -> 17.9 KB -> 8 blocks/CU
// (32 waves/CU) at unchanged tile geometry/work. R13 lesson: buy occupancy
// without adding halo work.

#define RADIUS 12
#define KS     25
#define TILE   64
#define PT     (TILE + 2 * RADIUS)   // 88
#define TA_LD  104                   // f16 row stride: 208B (16B-aligned)
#define IMG_W  512
#define IMG_H  512
#define PLANE  (IMG_W * IMG_H)
#define NPLANE 48

#define N_STAGE (PT * 11)            // 968 8px slots
#define N_H     (PT * (TILE / 8))    // 704 8-output slots

// Normalized 25-tap Gaussian, sigma=5
__device__ __constant__ float GW[KS] = {
    0.00453456f, 0.00718308f, 0.01093238f, 0.01598625f, 0.02245983f,
    0.03031760f, 0.03931982f, 0.04899550f, 0.05865827f, 0.06747307f,
    0.07456928f, 0.07918039f, 0.08077993f, 0.07918039f, 0.07456928f,
    0.06747307f, 0.05865827f, 0.04899550f, 0.03931982f, 0.03031760f,
    0.02245983f, 0.01598625f, 0.01093238f, 0.00718308f, 0.00453456f
};

__device__ __forceinline__ int reflect512(int i) {
    i = (i < 0) ? -i : i;
    return (i >= 512) ? (1022 - i) : i;
}

typedef _Float16 h2_t __attribute__((ext_vector_type(2)));

__device__ __forceinline__ unsigned h2u(__half2 h) {
    union { __half2 h; unsigned u; } x; x.h = h; return x.u;
}
__device__ __forceinline__ float u_lo(unsigned u) {
    union { unsigned u; __half2 h; } x; x.u = u;
    return __half2float(__low2half(x.h));
}
__device__ __forceinline__ float u_hi(unsigned u) {
    union { unsigned u; __half2 h; } x; x.u = u;
    return __half2float(__high2half(x.h));
}

#if __has_builtin(__builtin_amdgcn_fdot2)
__device__ __forceinline__ float fdot2u(unsigned a, unsigned b, float c) {
    union { unsigned u; h2_t h; } ua, ub;
    ua.u = a; ub.u = b;
    return __builtin_amdgcn_fdot2(ua.h, ub.h, c, false);
}
#else
__device__ __forceinline__ float fdot2u(unsigned a, unsigned b, float c) {
    return c + u_lo(a) * u_lo(b) + u_hi(a) * u_hi(b);
}
#endif

__device__ __forceinline__ uint4 h_slot(const __half (*tA)[TA_LD], int py, int g,
                                        const unsigned* W2, unsigned WE, unsigned WO) {
    const uint4 qa = *(const uint4*)&tA[py][g * 8];
    const uint4 qb = *(const uint4*)&tA[py][g * 8 + 8];
    const uint4 qc = *(const uint4*)&tA[py][g * 8 + 16];
    const uint4 qd = *(const uint4*)&tA[py][g * 8 + 24];

    unsigned P[16] = { qa.x, qa.y, qa.z, qa.w, qb.x, qb.y, qb.z, qb.w,
                       qc.x, qc.y, qc.z, qc.w, qd.x, qd.y, qd.z, qd.w };
    unsigned S[15];
#pragma unroll
    for (int i = 0; i < 15; ++i)
        S[i] = __builtin_amdgcn_alignbit(P[i + 1], P[i], 16);

    float acc[8];
#pragma unroll
    for (int h = 0; h < 4; ++h) {               // even outputs
        float a = 0.f;
#pragma unroll
        for (int m = 0; m < 12; ++m) a = fdot2u(P[h + m], W2[m], a);
        acc[2 * h] = fdot2u(P[h + 12], WE, a);
    }
#pragma unroll
    for (int h = 0; h < 4; ++h) {               // odd outputs
        float a = 0.f;
#pragma unroll
        for (int m = 0; m < 12; ++m) a = fdot2u(S[h + m], W2[m], a);
        acc[2 * h + 1] = fdot2u(P[h + 12], WO, a);
    }

    uint4 pk;
    pk.x = h2u(__floats2half2_rn(acc[0], acc[1]));
    pk.y = h2u(__floats2half2_rn(acc[2], acc[3]));
    pk.z = h2u(__floats2half2_rn(acc[4], acc[5]));
    pk.w = h2u(__floats2half2_rn(acc[6], acc[7]));
    return pk;
}

__global__ __launch_bounds__(256) void usm_fused_kernel(
    const float* __restrict__ img, const float* __restrict__ feat,
    float* __restrict__ out, float* __restrict__ out_param)
{
    __shared__ __half tileA[PT][TA_LD];   // 88x104 f16 = 17.9 KB (only LDS buffer)

    const int tid = threadIdx.x;
    const int tx0 = blockIdx.x * TILE, ty0 = blockIdx.y * TILE;
    const int zc = blockIdx.z, b = zc / 3;
    const float param = (tanhf(feat[b * 8]) * 0.5f + 0.5f) * 5.0f;
    const float* __restrict__ src = img + (size_t)zc * PLANE;
    const bool xedge = (blockIdx.x == 0) || (blockIdx.x == 7);

    unsigned W2[12];
#pragma unroll
    for (int m = 0; m < 12; ++m)
        W2[m] = h2u(__floats2half2_rn(GW[2 * m], GW[2 * m + 1]));
    const unsigned WE = h2u(__floats2half2_rn(GW[24], 0.f));
    const unsigned WO = h2u(__floats2half2_rn(0.f, GW[24]));

    // ---- Stage 88x88 padded tile as f16: 968 slots (iters 0-2 full, 3 partial) ----
#pragma unroll
    for (int it = 0; it < 4; ++it) {
        const int li = tid + it * 256;
        if (it < 3 || li < N_STAGE) {
            const int py = li / 11, s = li - py * 11;
            const int gy = reflect512(ty0 - RADIUS + py);
            const float* __restrict__ rowp = src + (size_t)gy * IMG_W;
            const int gx = tx0 - RADIUS + s * 8;
            float4 va, vb;
            if (!xedge) {
                va = *(const float4*)(rowp + gx);
                vb = *(const float4*)(rowp + gx + 4);
            } else {
                va.x = rowp[reflect512(gx)];     va.y = rowp[reflect512(gx + 1)];
                va.z = rowp[reflect512(gx + 2)]; va.w = rowp[reflect512(gx + 3)];
                vb.x = rowp[reflect512(gx + 4)]; vb.y = rowp[reflect512(gx + 5)];
                vb.z = rowp[reflect512(gx + 6)]; vb.w = rowp[reflect512(gx + 7)];
            }
            uint4 pk;
            pk.x = h2u(__floats2half2_rn(va.x, va.y));
            pk.y = h2u(__floats2half2_rn(va.z, va.w));
            pk.z = h2u(__floats2half2_rn(vb.x, vb.y));
            pk.w = h2u(__floats2half2_rn(vb.z, vb.w));
            *(uint4*)&tileA[py][s * 8] = pk;
        }
    }
    __syncthreads();

    // ---- H compute: 704 slots; hold outputs in regs (read phase) ----
    const int li1 = tid + 256, li2 = tid + 512;
    const bool act2 = (li2 < N_H);                 // tid < 192
    uint4 h0 = h_slot(tileA, tid >> 3, tid & 7, W2, WE, WO);
    uint4 h1 = h_slot(tileA, li1 >> 3, li1 & 7, W2, WE, WO);
    uint4 h2w = act2 ? h_slot(tileA, li2 >> 3, li2 & 7, W2, WE, WO)
                     : make_uint4(0, 0, 0, 0);
    __syncthreads();

    // ---- H write-back IN-PLACE into tileA cols 0..63 ----
    *(uint4*)&tileA[tid >> 3][(tid & 7) * 8] = h0;
    *(uint4*)&tileA[li1 >> 3][(li1 & 7) * 8] = h1;
    if (act2) *(uint4*)&tileA[li2 >> 3][(li2 & 7) * 8] = h2w;
    __syncthreads();

    // ---- V + epilogue: 4x4 micro-tile per thread (16x16 map) ----
    const int tx4 = (tid & 15) * 4, ry0 = (tid >> 4) * 4;
    float ax[4], ay[4], az[4], aw[4];
#pragma unroll
    for (int d = 0; d < 4; ++d) ax[d] = ay[d] = az[d] = aw[d] = 0.f;

#pragma unroll
    for (int k = 0; k < KS + 3; ++k) {            // 28 b64 row reads
        uint2 rd = *(const uint2*)&tileA[ry0 + k][tx4];
        const float c0 = u_lo(rd.x), c1 = u_hi(rd.x);
        const float c2 = u_lo(rd.y), c3 = u_hi(rd.y);
#pragma unroll
        for (int d = 0; d < 4; ++d) {
            const int kk = k - d;
            if (kk >= 0 && kk < KS) {
                const float wk = GW[kk];
                ax[d] += wk * c0; ay[d] += wk * c1;
                az[d] += wk * c2; aw[d] += wk * c3;
            }
        }
    }

    float* __restrict__ dst = out + (size_t)zc * PLANE;
#pragma unroll
    for (int d = 0; d < 4; ++d) {
        const int oy = ty0 + ry0 + d;
        float4 v = *(const float4*)(src + (size_t)oy * IMG_W + tx0 + tx4);  // exact f32
        float4 o;
        o.x = v.x + param * (v.x - ax[d]);
        o.y = v.y + param * (v.y - ay[d]);
        o.z = v.z + param * (v.z - az[d]);
        o.w = v.w + param * (v.w - aw[d]);
        *(float4*)(dst + (size_t)oy * IMG_W + tx0 + tx4) = o;
    }

    if (tid == 0 && blockIdx.x == 0 && blockIdx.y == 0 && (zc - b * 3) == 0)
        out_param[b] = param;
}

extern "C" void kernel_launch(void* const* d_in, const int* in_sizes, int n_in,
                              void* d_out, int out_size, void* d_ws, size_t ws_size,
                              hipStream_t stream) {
    const float* img  = (const float*)d_in[0];
    const float* feat = (const float*)d_in[1];
    float* out       = (float*)d_out;
    float* out_param = (float*)d_out + (size_t)NPLANE * PLANE;

    usm_fused_kernel<<<dim3(8, 8, NPLANE), 256, 0, stream>>>(img, feat, out, out_param);
}